// Round 12
// baseline (360.148 us; speedup 1.0000x reference)
//
#include <hip/hip_runtime.h>

// CausalAttention: B=4, S=4096, D=1024 (single head, head_dim=1024)
// v12: fused-cast -> QKV GEMM -> S-GEMM+exp -> PV GEMM (8-phase, fused l-red).
// R12: qkv+sgemm restructured for 2-blocks/CU co-residency (TLP hides barrier
// drains, m114): 256x128 tile, 8 waves as 4Mx2N (wave tile 64x64 -> acc=64
// AGPR), BK=32 dbuf LDS=48KB, __launch_bounds__(512,4) caps regs at 128/wave.
// Simple 2-phase sync (R5-proven); BK=32 LDS bijection slot = c ^ ((r>>1)&3)
// (lane-linear gld_lds dest, uniform read-quad distribution).
// pv_gemm = R11 8-phase (only lpart layout updated: stride 32, kt128 grain).
// ws (u16): Wqkv[3M] | X[16M, zero-tile after qkv] | Q[16M] | K[16M] |
//   VT[16M] | Spack[34.6M packed 128-tiles] | lpart[16384*32 f32 = 2MB]

typedef unsigned short u16;
typedef unsigned int u32;
typedef __attribute__((ext_vector_type(8))) short bf16x8;
typedef __attribute__((ext_vector_type(4))) float f32x4;
typedef __attribute__((ext_vector_type(8))) unsigned short u16x8;

__device__ __forceinline__ u16 f2bf(float f) {
  union { float f; unsigned u; } v; v.f = f;
  unsigned r = v.u + 0x7FFFu + ((v.u >> 16) & 1u);  // RNE
  return (u16)(r >> 16);
}
__device__ __forceinline__ float bf2f(u16 h) {
  union { unsigned u; float f; } v; v.u = ((unsigned)h) << 16;
  return v.f;
}
__device__ __forceinline__ f32x4 mfma16(bf16x8 a, bf16x8 b, f32x4 c) {
  return __builtin_amdgcn_mfma_f32_16x16x32_bf16(a, b, c, 0, 0, 0);
}
__device__ __forceinline__ void gld_lds16(const u16* g, u16* l) {
  __builtin_amdgcn_global_load_lds(
      (const __attribute__((address_space(1))) u32*)g,
      (__attribute__((address_space(3))) u32*)l, 16, 0, 0);
}
#define BAR() do { __builtin_amdgcn_s_barrier(); \
                   __builtin_amdgcn_sched_barrier(0); } while (0)
#define LGKM0() do { asm volatile("s_waitcnt lgkmcnt(0)" ::: "memory"); \
                     __builtin_amdgcn_sched_barrier(0); } while (0)
#define VMC(n) asm volatile("s_waitcnt vmcnt(" #n ")" ::: "memory")

// ---------------- fused cast f32 -> bf16 ----------------
__global__ __launch_bounds__(256)
void cast_all(const float* __restrict__ x, const float* __restrict__ Wq,
              const float* __restrict__ Wk, const float* __restrict__ Wv,
              u16* __restrict__ wX, u16* __restrict__ wWqkv) {
  int i = blockIdx.x * 256 + threadIdx.x;
  const float* src; u16* dst; int j;
  if (i < 2097152)        { src = x;  dst = wX;                j = i; }
  else if (i < 2228224)   { src = Wq; dst = wWqkv;             j = i - 2097152; }
  else if (i < 2359296)   { src = Wk; dst = wWqkv + 1048576;   j = i - 2228224; }
  else if (i < 2490368)   { src = Wv; dst = wWqkv + 2097152;   j = i - 2359296; }
  else return;
  const float4* s4 = (const float4*)src;
  float4 a = s4[2*j], b = s4[2*j+1];
  u16x8 o;
  o[0]=f2bf(a.x); o[1]=f2bf(a.y); o[2]=f2bf(a.z); o[3]=f2bf(a.w);
  o[4]=f2bf(b.x); o[5]=f2bf(b.y); o[6]=f2bf(b.z); o[7]=f2bf(b.w);
  ((u16x8*)dst)[j] = o;
}

// Co-resident GEMM core: 256x128 tile, BK=32, 8 waves as 4Mx2N (64x64/wave),
// dbuf 2-phase. Abase: 256-row panel, Bbase: 128-row panel (both stride 1024).
// LDS slot bijection: row r, logical chunk c (of 4) stored at slot c^((r>>1)&3).
#define GEMM_CO_CORE(Abase, Bbase)                                            \
  auto stage = [&](int s, int k0) {                                           \
    _Pragma("unroll")                                                         \
    for (int i = 0; i < 2; ++i) {                                             \
      int ci = i * 512 + tid;                   /* 1024 A chunks */           \
      int r  = ci >> 2;                                                       \
      int c  = (ci & 3) ^ ((r >> 1) & 3);                                     \
      gld_lds16(Abase + (size_t)r * 1024 + k0 + c * 8, &At[s][ci * 8]);       \
    }                                                                         \
    {                                                                         \
      int ci = tid;                              /* 512 B chunks */           \
      int r  = ci >> 2;                                                       \
      int c  = (ci & 3) ^ ((r >> 1) & 3);                                     \
      gld_lds16(Bbase + (size_t)r * 1024 + k0 + c * 8, &Bt[s][ci * 8]);       \
    }                                                                         \
  };                                                                          \
  auto compute = [&](int s) {                                                 \
    bf16x8 af[4], bfr[4];                                                     \
    _Pragma("unroll")                                                         \
    for (int m = 0; m < 4; ++m) {                                             \
      int row = wm * 64 + m * 16 + c16;                                       \
      af[m] = *(const bf16x8*)&At[s][row * 32 + ((g ^ ((row >> 1) & 3)) * 8)];\
    }                                                                         \
    _Pragma("unroll")                                                         \
    for (int n = 0; n < 4; ++n) {                                             \
      int row = wn * 64 + n * 16 + c16;                                       \
      bfr[n] = *(const bf16x8*)&Bt[s][row * 32 + ((g ^ ((row >> 1) & 3)) * 8)];\
    }                                                                         \
    _Pragma("unroll")                                                         \
    for (int m = 0; m < 4; ++m)                                               \
      _Pragma("unroll")                                                       \
      for (int n = 0; n < 4; ++n)                                             \
        acc[m][n] = mfma16(af[m], bfr[n], acc[m][n]);                         \
  };                                                                          \
  stage(0, 0);                                                                \
  __syncthreads();                                                            \
  int cur = 0;                                                                \
  for (int t = 0; t < 32; ++t) {                                              \
    if (t < 31) stage(cur ^ 1, (t + 1) * 32);                                 \
    compute(cur);                                                             \
    __syncthreads();                                                          \
    cur ^= 1;                                                                 \
  }

// ---------------- fused QKV GEMM: 256x128, 2 blocks/CU, XCD-striped ----------------
__global__ __launch_bounds__(512, 4)
void qkv_gemm(const u16* __restrict__ X, const u16* __restrict__ W,
              u16* __restrict__ Qo, u16* __restrict__ Ko, u16* __restrict__ VTo) {
  __shared__ __align__(16) u16 At[2][256 * 32];
  __shared__ __align__(16) u16 Bt[2][128 * 32];
  const int tid = threadIdx.x;
  const int w = tid >> 6, lane = tid & 63;
  const int g = lane >> 4, c16 = lane & 15;
  const int wm = w >> 1, wn = w & 1;           // wave out: rows wm*64, cols wn*64
  const int lid = blockIdx.x;
  const int xcd = lid & 7, gg = lid >> 3;      // gg in [0,192)
  const int M0 = ((xcd << 3) | (gg & 7)) * 256;
  const int N0 = (gg >> 3) * 128;              // 24 N-tiles
  const u16* Abase = X + (size_t)M0 * 1024;
  const u16* Bbase = W + (size_t)N0 * 1024;

  f32x4 acc[4][4] = {};
  GEMM_CO_CORE(Abase, Bbase);

  const int which = N0 >> 10;                  // 0=Q, 1=K, 2=V
  const int colbase = N0 & 1023;
#pragma unroll
  for (int m = 0; m < 4; ++m) {
#pragma unroll
    for (int n = 0; n < 4; ++n) {
#pragma unroll
      for (int r = 0; r < 4; ++r) {
        int gm  = M0 + wm * 64 + m * 16 + 4 * g + r;
        int col = colbase + wn * 64 + n * 16 + c16;
        u16 hv = f2bf(acc[m][n][r]);
        if (which == 0) {
          Qo[(size_t)gm * 1024 + col] = hv;
        } else if (which == 1) {
          Ko[(size_t)gm * 1024 + col] = hv;
        } else {
          int b = gm >> 12, s2 = gm & 4095;
          VTo[((size_t)((b << 10) + col)) * 4096 + s2] = hv;
        }
      }
    }
  }
}

// ---------------- S-GEMM + exp: 256x128 causal tiles, 2 blocks/CU ----------------
// grid.x = 272 per batch (qt in [0,16), kt128 in [0, 2qt+2)), XCD-chunked.
__global__ __launch_bounds__(512, 4)
void sgemm_exp(const u16* __restrict__ Q, const u16* __restrict__ K,
               u16* __restrict__ Spack, float* __restrict__ lpart) {
  __shared__ __align__(16) u16 At[2][256 * 32];
  __shared__ __align__(16) u16 Bt[2][128 * 32];
  __shared__ float lsum[256][2];
  const int tid = threadIdx.x;
  const int w = tid >> 6, lane = tid & 63;
  const int g = lane >> 4, c16 = lane & 15;
  const int wm = w >> 1, wn = w & 1;
  const int b = blockIdx.y;

  int L = (blockIdx.x & 7) * 34 + (blockIdx.x >> 3);   // bijective (272 = 34*8)
  int qt = 0;
  while ((qt + 1) * (qt + 2) <= L) ++qt;               // tri base qt(qt+1)
  const int kt128 = L - qt * (qt + 1);

  const u16* Abase = Q + (size_t)b * 4096 * 1024 + (size_t)qt * 256 * 1024;
  const u16* Bbase = K + (size_t)b * 4096 * 1024 + (size_t)kt128 * 128 * 1024;

  f32x4 acc[4][4] = {};
  GEMM_CO_CORE(Abase, Bbase);

  // epilogue: exp + causal mask, packed 128-tile store, row-sum partials.
  const int qt128 = 2 * qt + (wm >> 1);        // uniform per thread
  const bool exists = (kt128 <= qt128);
  u16* Sb = Spack + (((size_t)b * 528 + (size_t)(qt128 * (qt128 + 1)) / 2 + kt128) << 14);
  const int q0 = qt * 256, k0g = kt128 * 128;
  float psum[4][4];
#pragma unroll
  for (int m = 0; m < 4; ++m)
#pragma unroll
    for (int r = 0; r < 4; ++r) psum[m][r] = 0.f;
#pragma unroll
  for (int m = 0; m < 4; ++m) {
#pragma unroll
    for (int n = 0; n < 4; ++n) {
#pragma unroll
      for (int r = 0; r < 4; ++r) {
        int rl = wm * 64 + m * 16 + 4 * g + r;     // 0..255
        int cl = wn * 64 + n * 16 + c16;           // 0..127
        float s = acc[m][n][r] * 0.03125f;         // 1/sqrt(1024)
        float p = (k0g + cl <= q0 + rl) ? __expf(s) : 0.f;
        u16 pb = f2bf(p);
        if (exists) Sb[(rl & 127) * 128 + cl] = pb;
        psum[m][r] += bf2f(pb);
      }
    }
  }
#pragma unroll
  for (int m = 0; m < 4; ++m)
#pragma unroll
    for (int r = 0; r < 4; ++r) {
      float v = psum[m][r];
      v += __shfl_xor(v, 1, 64);
      v += __shfl_xor(v, 2, 64);
      v += __shfl_xor(v, 4, 64);
      v += __shfl_xor(v, 8, 64);
      psum[m][r] = v;
    }
  if (c16 == 0) {
#pragma unroll
    for (int m = 0; m < 4; ++m)
#pragma unroll
      for (int r = 0; r < 4; ++r)
        lsum[wm * 64 + m * 16 + 4 * g + r][wn] = psum[m][r];
  }
  __syncthreads();
  if (tid < 256) {
    float v = lsum[tid][0] + lsum[tid][1];
    lpart[((size_t)b * 4096 + q0 + tid) * 32 + kt128] = v;
  }
}

// ---------------- PV GEMM: 256x128 paired q-tiles, 8-phase (R11), fused l-reduce ----------------
__global__ __launch_bounds__(512, 1)
void pv_gemm(const u16* __restrict__ Spack, const u16* __restrict__ VT,
             const u16* __restrict__ ztile, const float* __restrict__ lpart,
             float* __restrict__ Out) {
  __shared__ __align__(16) u16 At[2][256 * 64];
  __shared__ __align__(16) u16 Bt[2][128 * 64];
  __shared__ float linv_lds[512];
  const int tid = threadIdx.x;
  const int w = tid >> 6, lane = tid & 63;
  const int g = lane >> 4, c16 = lane & 15;
  const int wm = w >> 1, wn = w & 1;
  const int pp = blockIdx.x;
  const int d0 = blockIdx.y;
  const int b  = blockIdx.z;

  const u16* Sp_b = Spack + (size_t)b * 528 * 16384;
  const u16* VTb  = VT + (size_t)b * 1024 * 4096;
  float* Ob = Out + (size_t)b * 4096 * 1024;

  // fused l-reduce (lpart stride 32; nt = qt128+1)
  {
    const int QTr = (tid < 256) ? pp : (15 - pp);
    const int row = QTr * 256 + (tid & 255);
    const int nt  = 2 * QTr + 1 + ((tid >> 7) & 1);
    const float* p = lpart + ((size_t)b * 4096 + row) * 32;
    float s = 0.f;
    for (int i = 0; i < nt; ++i) s += p[i];
    linv_lds[tid] = 1.f / s;
  }

  for (int pass = 0; pass < 2; ++pass) {
    const int QT = pass == 0 ? pp : 15 - pp;
    const int M0 = QT * 256;
    const int nsteps = (QT + 1) * 4;
    const int niter  = nsteps >> 1;
    const int tLo = 2 * QT;
    const size_t triLo = (size_t)(tLo * (tLo + 1)) / 2;
    const size_t triHi = (size_t)((tLo + 1) * (tLo + 2)) / 2;

    f32x4 acc[4][4] = {};

    auto stA = [&](int bufi, int half, int tt) {
      const int kt128 = tt >> 1;
      const int koff = (tt & 1) * 64;
      const u16* base;
      if (half == 0) base = (kt128 <= tLo) ? Sp_b + ((triLo + kt128) << 14) : ztile;
      else           base = Sp_b + ((triHi + kt128) << 14);
#pragma unroll
      for (int i = 0; i < 2; ++i) {
        int ci = (half * 2 + i) * 512 + tid;
        int r = ci >> 3;
        int c = (ci & 7) ^ (r & 7);
        gld_lds16(base + (size_t)(r & 127) * 128 + koff + c * 8, &At[bufi][ci * 8]);
      }
    };
    auto stB = [&](int bufi, int tt) {
      const int kv0 = tt * 64;
#pragma unroll
      for (int i = 0; i < 2; ++i) {
        int ci = i * 512 + tid;
        int r = ci >> 3;
        int c = (ci & 7) ^ (r & 7);
        gld_lds16(VTb + (size_t)(d0 * 128 + r) * 4096 + kv0 + c * 8, &Bt[bufi][ci * 8]);
      }
    };

    bf16x8 af[4][2], bfr[4][2];
    auto readA = [&](int bufi, int mb) {
#pragma unroll
      for (int m = 0; m < 2; ++m)
#pragma unroll
        for (int dk = 0; dk < 2; ++dk) {
          int row = wm * 64 + (mb + m) * 16 + c16;
          int ch = dk * 4 + g;
          af[mb + m][dk] = *(const bf16x8*)&At[bufi][row * 64 + ((ch ^ (row & 7)) * 8)];
        }
    };
    auto readB = [&](int bufi, int nb) {
#pragma unroll
      for (int n = 0; n < 2; ++n)
#pragma unroll
        for (int dk = 0; dk < 2; ++dk) {
          int row = wn * 64 + (nb + n) * 16 + c16;
          int ch = dk * 4 + g;
          bfr[nb + n][dk] = *(const bf16x8*)&Bt[bufi][row * 64 + ((ch ^ (row & 7)) * 8)];
        }
    };
    auto domfma = [&](int mb, int nb) {
      __builtin_amdgcn_s_setprio(1);
#pragma unroll
      for (int dk = 0; dk < 2; ++dk)
#pragma unroll
        for (int m = 0; m < 2; ++m)
#pragma unroll
          for (int n = 0; n < 2; ++n)
            acc[mb + m][nb + n] = mfma16(af[mb + m][dk], bfr[nb + n][dk], acc[mb + m][nb + n]);
      __builtin_amdgcn_s_setprio(0);
    };

    stA(0, 0, 0); stA(0, 1, 0); stB(0, 0);
    stA(1, 0, 1); stA(1, 1, 1); stB(1, 1);
    VMC(6);
    BAR();
    for (int it = 0; it < niter; ++it) {
      const bool pf = (it + 1 < niter);
      const int t2 = 2 * it + 2, t3 = 2 * it + 3;
      readA(0, 0); readB(0, 0);
      BAR(); LGKM0();
      domfma(0, 0);
      BAR();
      readA(0, 2);
      BAR(); LGKM0();
      domfma(2, 0);
      BAR();
      readB(0, 2);
      if (pf) { stA(0, 0, t2); stA(0, 1, t2); }
      BAR(); LGKM0();
      domfma(2, 2);
      BAR();
      if (pf) stB(0, t2);
      BAR();
      domfma(0, 2);
      if (pf) { VMC(6); } else { VMC(0); }
      BAR();
      readA(1, 0); readB(1, 0);
      BAR(); LGKM0();
      domfma(0, 0);
      BAR();
      readA(1, 2);
      BAR(); LGKM0();
      domfma(2, 0);
      BAR();
      readB(1, 2);
      if (pf) { stA(1, 0, t3); stA(1, 1, t3); }
      BAR(); LGKM0();
      domfma(2, 2);
      BAR();
      if (pf) stB(1, t3);
      BAR();
      domfma(0, 2);
      if (pf) { VMC(6); } else { VMC(0); }
      BAR();
    }

    const float* lb = linv_lds + pass * 256;
#pragma unroll
    for (int m = 0; m < 4; ++m) {
#pragma unroll
      for (int r = 0; r < 4; ++r) {
        int rl = wm * 64 + m * 16 + 4 * g + r;
        float li = lb[rl];
#pragma unroll
        for (int n = 0; n < 4; ++n) {
          int dcol = d0 * 128 + wn * 64 + n * 16 + c16;
          Ob[(size_t)(M0 + rl) * 1024 + dcol] = acc[m][n][r] * li;
        }
      }
    }
  }
}

// ---------------- fallback attn (R1, proven 558us) ----------------
__global__ __launch_bounds__(512, 2)
void attn_kernel(const u16* __restrict__ Q, const u16* __restrict__ K,
                 const u16* __restrict__ VT, float* __restrict__ Out) {
  __shared__ u16 kv_lds[32 * 1024];
  __shared__ float s_part[4][32][33];
  __shared__ u16 p_lds[32 * 40];
  __shared__ float l_lds[32];

  const int tid = threadIdx.x;
  const int w = tid >> 6, lane = tid & 63;
  const int g = lane >> 4, c16 = lane & 15;
  const int b  = blockIdx.x & 3;
  const int qb = 127 - (blockIdx.x >> 2);
  const int qs = qb * 32;
  const int kh = w & 1, dq = w >> 1;

  const u16* Qb  = Q  + (size_t)b * 4096 * 1024;
  const u16* Kb  = K  + (size_t)b * 4096 * 1024;
  const u16* VTb = VT + (size_t)b * 1024 * 4096;

  bf16x8 qfrag[2][8];
#pragma unroll
  for (int qh = 0; qh < 2; ++qh)
#pragma unroll
    for (int dk = 0; dk < 8; ++dk)
      qfrag[qh][dk] = *(const bf16x8*)(Qb + (size_t)(qs + qh * 16 + c16) * 1024
                                       + dq * 256 + dk * 32 + g * 8);

  f32x4 oacc[2][8] = {};
  if (tid < 32) l_lds[tid] = 0.f;

  const int qrow_p = tid >> 4;
  const int kk     = tid & 15;
  const int gq     = qs + qrow_p;

  for (int j = 0; j <= qb; ++j) {
    const int kv0 = j * 32;
    __syncthreads();
    uint4 rk[8];
#pragma unroll
    for (int i = 0; i < 8; ++i) {
      int ci = i * 512 + tid;
      int r  = ci >> 7;
      int c  = (ci & 127) ^ (r & 7);
      rk[i] = *(const uint4*)(Kb + (size_t)(kv0 + r) * 1024 + c * 8);
    }
#pragma unroll
    for (int i = 0; i < 8; ++i)
      *(uint4*)&kv_lds[(size_t)(i * 512 + tid) * 8] = rk[i];
    __syncthreads();
    f32x4 sacc[2] = {};
#pragma unroll
    for (int dk = 0; dk < 8; ++dk) {
      int kvrow = kh * 16 + c16;
      int ch    = dq * 32 + dk * 4 + g;
      bf16x8 kf = *(const bf16x8*)&kv_lds[kvrow * 1024 + ((ch ^ (kvrow & 7)) * 8)];
      sacc[0] = mfma16(qfrag[0][dk], kf, sacc[0]);
      sacc[1] = mfma16(qfrag[1][dk], kf, sacc[1]);
    }
#pragma unroll
    for (int qh = 0; qh < 2; ++qh)
#pragma unroll
      for (int r = 0; r < 4; ++r)
        s_part[dq][qh * 16 + 4 * g + r][kh * 16 + c16] = sacc[qh][r];
    __syncthreads();
    uint4 rv[8];
#pragma unroll
    for (int i = 0; i < 8; ++i) {
      int ci = i * 512 + tid;
      int d  = ((ci >> 6) << 4) + (ci & 15);
      int c  = (ci >> 4) & 3;
      rv[i] = *(const uint4*)(VTb + (size_t)d * 4096 + kv0 + c * 8);
    }
    {
      float psum = 0.f;
#pragma unroll
      for (int h = 0; h < 2; ++h) {
        int kcol = kk + h * 16;
        float s = s_part[0][qrow_p][kcol] + s_part[1][qrow_p][kcol]
                + s_part[2][qrow_p][kcol] + s_part[3][qrow_p][kcol];
        s *= 0.03125f;
        float p = (kv0 + kcol <= gq) ? __expf(s) : 0.f;
        u16 pb = f2bf(p);
        p_lds[qrow_p * 40 + kcol] = pb;
        psum += bf2f(pb);
      }
#pragma unroll
      for (int off = 1; off < 16; off <<= 1)
        psum += __shfl_xor(psum, off, 64);
      if (kk == 0) l_lds[qrow_p] += psum;
    }
#pragma unroll
    for (int i = 0; i < 8; ++i)
      *(uint4*)&kv_lds[(size_t)(i * 512 + tid) * 8] = rv[i];
    __syncthreads();
    bf16x8 pa0 = *(const bf16x8*)&p_lds[(0  + c16) * 40 + g * 8];
    bf16x8 pa1 = *(const bf16x8*)&p_lds[(16 + c16) * 40 + g * 8];
#pragma unroll
    for (int f = 0; f < 8; ++f) {
      int dcol = w * 128 + f * 16 + c16;
      int pos  = (dcol >> 4) * 64 + g * 16 + (dcol & 15);
      bf16x8 vf = *(const bf16x8*)&kv_lds[(size_t)pos * 8];
      oacc[0][f] = mfma16(pa0, vf, oacc[0][f]);
      oacc[1][f] = mfma16(pa1, vf, oacc[1][f]);
    }
  }

  float* Ob = Out + (size_t)b * 4096 * 1024;
#pragma unroll
  for (int qh = 0; qh < 2; ++qh) {
#pragma unroll
    for (int r = 0; r < 4; ++r) {
      int ql = qh * 16 + 4 * g + r;
      float linvv = 1.f / l_lds[ql];
#pragma unroll
      for (int f = 0; f < 8; ++f)
        Ob[(size_t)(qs + ql) * 1024 + w * 128 + f * 16 + c16] = oacc[qh][f][r] * linvv;
    }
  }
}

extern "C" void kernel_launch(void* const* d_in, const int* in_sizes, int n_in,
                              void* d_out, int out_size, void* d_ws, size_t ws_size,
                              hipStream_t stream) {
  const float* x  = (const float*)d_in[0];
  const float* Wq = (const float*)d_in[1];
  const float* Wk = (const float*)d_in[2];
  const float* Wv = (const float*)d_in[3];
  float* out = (float*)d_out;

  u16* ws    = (u16*)d_ws;
  u16* wWqkv = ws;                                   // 3M elems
  u16* wX    = wWqkv + (size_t)3 * 1024 * 1024;      // dead after qkv -> zero tile
  u16* wQ    = wX + (size_t)16384 * 1024;
  u16* wK    = wQ + (size_t)16384 * 1024;
  u16* wVT   = wK + (size_t)16384 * 1024;            // [4][1024][4096]
  u16* wSp   = wVT + (size_t)16384 * 1024;           // packed 128-tile triangle
  float* lpart = (float*)(ws + (size_t)104857600);   // 16384*32 f32 (2MB)

  cast_all<<<dim3(9728), 256, 0, stream>>>(x, Wq, Wk, Wv, wX, wWqkv);

  qkv_gemm<<<dim3(1536), 512, 0, stream>>>(wX, wWqkv, wQ, wK, wVT);

  if (ws_size >= (size_t)211877888) {
    hipMemsetAsync(wX, 0, 32768, stream);            // zero tile for absent causal tiles
    sgemm_exp<<<dim3(272, 4), 512, 0, stream>>>(wQ, wK, wSp, lpart);
    pv_gemm<<<dim3(8, 8, 4), 512, 0, stream>>>(wSp, wVT, wX, lpart, out);
  } else {
    attn_kernel<<<dim3(512), 512, 0, stream>>>(wQ, wK, wVT, out);
  }
}

// Round 13
// 353.027 us; speedup vs baseline: 1.0202x; 1.0202x over previous
//
#include <hip/hip_runtime.h>

// CausalAttention: B=4, S=4096, D=1024 (single head, head_dim=1024)
// v13 = v11 (best, 356.1us) + ztile zero-fill folded into cast_all (drops the
// hipMemsetAsync launch; ztile relocated to the dead old-linv ws slot).
// Pipeline: fused-cast -> QKV GEMM (VT, XCD-striped, 8-phase counted-vmcnt)
//   -> S-GEMM+exp (causal triangle, XCD-chunked, 8-phase) -> PV GEMM
//   (paired q-tiles, 8-phase, fused l-reduce). No-max softmax (validated R1).
// ws (u16): Wqkv[3M] | X[16M] | Q[16M] | K[16M] | VT[16M] | Spack[34.6M] |
//   lpart[16384*16 f32] @104857600 | ztile[16384] @105906176

typedef unsigned short u16;
typedef unsigned int u32;
typedef __attribute__((ext_vector_type(8))) short bf16x8;
typedef __attribute__((ext_vector_type(4))) float f32x4;
typedef __attribute__((ext_vector_type(8))) unsigned short u16x8;

__device__ __forceinline__ u16 f2bf(float f) {
  union { float f; unsigned u; } v; v.f = f;
  unsigned r = v.u + 0x7FFFu + ((v.u >> 16) & 1u);  // RNE
  return (u16)(r >> 16);
}
__device__ __forceinline__ float bf2f(u16 h) {
  union { unsigned u; float f; } v; v.u = ((unsigned)h) << 16;
  return v.f;
}
__device__ __forceinline__ f32x4 mfma16(bf16x8 a, bf16x8 b, f32x4 c) {
  return __builtin_amdgcn_mfma_f32_16x16x32_bf16(a, b, c, 0, 0, 0);
}
__device__ __forceinline__ void gld_lds16(const u16* g, u16* l) {
  __builtin_amdgcn_global_load_lds(
      (const __attribute__((address_space(1))) u32*)g,
      (__attribute__((address_space(3))) u32*)l, 16, 0, 0);
}
#define BAR() do { __builtin_amdgcn_s_barrier(); \
                   __builtin_amdgcn_sched_barrier(0); } while (0)
#define LGKM0() do { asm volatile("s_waitcnt lgkmcnt(0)" ::: "memory"); \
                     __builtin_amdgcn_sched_barrier(0); } while (0)
#define VMC(n) asm volatile("s_waitcnt vmcnt(" #n ")" ::: "memory")

// ---------------- fused cast f32 -> bf16 + ztile zero-fill ----------------
__global__ __launch_bounds__(256)
void cast_all(const float* __restrict__ x, const float* __restrict__ Wq,
              const float* __restrict__ Wk, const float* __restrict__ Wv,
              u16* __restrict__ wX, u16* __restrict__ wWqkv,
              u16* __restrict__ zt) {
  int i = blockIdx.x * 256 + threadIdx.x;
  const float* src; u16* dst; int j;
  if (i < 2097152)        { src = x;  dst = wX;                j = i; }
  else if (i < 2228224)   { src = Wq; dst = wWqkv;             j = i - 2097152; }
  else if (i < 2359296)   { src = Wk; dst = wWqkv + 1048576;   j = i - 2228224; }
  else if (i < 2490368)   { src = Wv; dst = wWqkv + 2097152;   j = i - 2359296; }
  else if (i < 2492416)   {                       // zero tile for pv_gemm
    u16x8 z = {0, 0, 0, 0, 0, 0, 0, 0};
    ((u16x8*)zt)[i - 2490368] = z;
    return;
  }
  else return;
  const float4* s4 = (const float4*)src;
  float4 a = s4[2*j], b = s4[2*j+1];
  u16x8 o;
  o[0]=f2bf(a.x); o[1]=f2bf(a.y); o[2]=f2bf(a.z); o[3]=f2bf(a.w);
  o[4]=f2bf(b.x); o[5]=f2bf(b.y); o[6]=f2bf(b.z); o[7]=f2bf(b.w);
  ((u16x8*)dst)[j] = o;
}

// 8-phase GEMM core (qkv / sgemm shared). 256x256 tile, 8 waves (wr 2M x wc 4N),
// BK=64, 2 K-tiles per iteration. Reads: P1 af[0-3]+bfr[0-1], P2 af[4-7],
// P3 bfr[2-3]. Stages: P3 A(t+2), P4 B(t+2), P7 A(t+3), P8 B(t+3).
// vmcnt(8) at P4/P8 (R10-validated: stage-to-use distance 4-5 phases).
#define GEMM8_CORE(Abase, Bbase)                                              \
  auto stageA = [&](int bufi, int h, int t) {                                 \
    _Pragma("unroll")                                                         \
    for (int i = 0; i < 2; ++i) {                                             \
      int ci = i * 512 + tid;                                                 \
      int r  = ci >> 3;                                                       \
      int c  = (ci & 7) ^ (r & 7);                                            \
      gld_lds16(Abase + (size_t)(h * 128 + r) * 1024 + t * 64 + c * 8,        \
                &At[bufi][h][ci * 8]);                                        \
    }                                                                         \
  };                                                                          \
  auto stageB = [&](int bufi, int h, int t) {                                 \
    _Pragma("unroll")                                                         \
    for (int i = 0; i < 2; ++i) {                                             \
      int ci = i * 512 + tid;                                                 \
      int r  = ci >> 3;                                                       \
      int c  = (ci & 7) ^ (r & 7);                                            \
      gld_lds16(Bbase + (size_t)(h * 128 + r) * 1024 + t * 64 + c * 8,        \
                &Bt[bufi][h][ci * 8]);                                        \
    }                                                                         \
  };                                                                          \
  bf16x8 af[8][2], bfr[4][2];                                                 \
  auto readA = [&](int bufi, int mb) {                                        \
    _Pragma("unroll")                                                         \
    for (int m = 0; m < 4; ++m)                                               \
      _Pragma("unroll")                                                       \
      for (int dk = 0; dk < 2; ++dk) {                                        \
        int r  = (mb + m) * 16 + c16;                                         \
        int ch = dk * 4 + g;                                                  \
        af[mb + m][dk] =                                                      \
            *(const bf16x8*)&At[bufi][wr][r * 64 + ((ch ^ (r & 7)) * 8)];     \
      }                                                                       \
  };                                                                          \
  auto readB = [&](int bufi, int nb) {                                        \
    _Pragma("unroll")                                                         \
    for (int n = 0; n < 2; ++n)                                               \
      _Pragma("unroll")                                                       \
      for (int dk = 0; dk < 2; ++dk) {                                        \
        int r  = (wc & 1) * 64 + (nb + n) * 16 + c16;                         \
        int ch = dk * 4 + g;                                                  \
        bfr[nb + n][dk] =                                                     \
            *(const bf16x8*)&Bt[bufi][wc >> 1][r * 64 + ((ch ^ (r & 7)) * 8)];\
      }                                                                       \
  };                                                                          \
  auto domfma = [&](int mb, int nb) {                                         \
    __builtin_amdgcn_s_setprio(1);                                            \
    _Pragma("unroll")                                                         \
    for (int dk = 0; dk < 2; ++dk)                                            \
      _Pragma("unroll")                                                       \
      for (int m = 0; m < 4; ++m)                                             \
        _Pragma("unroll")                                                     \
        for (int n = 0; n < 2; ++n)                                           \
          acc[mb + m][nb + n] =                                               \
              mfma16(af[mb + m][dk], bfr[nb + n][dk], acc[mb + m][nb + n]);   \
    __builtin_amdgcn_s_setprio(0);                                            \
  };                                                                          \
  stageA(0, 0, 0); stageA(0, 1, 0); stageB(0, 0, 0); stageB(0, 1, 0);         \
  stageA(1, 0, 1); stageA(1, 1, 1); stageB(1, 0, 1); stageB(1, 1, 1);         \
  VMC(8);                                                                     \
  BAR();                                                                      \
  for (int it = 0; it < 8; ++it) {                                            \
    const bool pf = (it < 7);                                                 \
    const int t2 = 2 * it + 2, t3 = 2 * it + 3;                               \
    readA(0, 0); readB(0, 0);                                                 \
    BAR(); LGKM0();                                                           \
    domfma(0, 0);                                                             \
    BAR();                                                                    \
    readA(0, 4);                                                              \
    BAR(); LGKM0();                                                           \
    domfma(4, 0);                                                             \
    BAR();                                                                    \
    readB(0, 2);                                                              \
    if (pf) { stageA(0, 0, t2); stageA(0, 1, t2); }                           \
    BAR(); LGKM0();                                                           \
    domfma(4, 2);                                                             \
    BAR();                                                                    \
    if (pf) { stageB(0, 0, t2); stageB(0, 1, t2); }                           \
    BAR();                                                                    \
    domfma(0, 2);                                                             \
    if (pf) { VMC(8); } else { VMC(0); }                                      \
    BAR();                                                                    \
    readA(1, 0); readB(1, 0);                                                 \
    BAR(); LGKM0();                                                           \
    domfma(0, 0);                                                             \
    BAR();                                                                    \
    readA(1, 4);                                                              \
    BAR(); LGKM0();                                                           \
    domfma(4, 0);                                                             \
    BAR();                                                                    \
    readB(1, 2);                                                              \
    if (pf) { stageA(1, 0, t3); stageA(1, 1, t3); }                           \
    BAR(); LGKM0();                                                           \
    domfma(4, 2);                                                             \
    BAR();                                                                    \
    if (pf) { stageB(1, 0, t3); stageB(1, 1, t3); }                           \
    BAR();                                                                    \
    domfma(0, 2);                                                             \
    if (pf) { VMC(8); } else { VMC(0); }                                      \
    BAR();                                                                    \
  }

// ---------------- fused QKV GEMM: 256x256 8-phase, XCD-striped ----------------
__global__ __launch_bounds__(512, 1)
void qkv_gemm(const u16* __restrict__ X, const u16* __restrict__ W,
              u16* __restrict__ Qo, u16* __restrict__ Ko, u16* __restrict__ VTo) {
  __shared__ __align__(16) u16 At[2][2][128 * 64];
  __shared__ __align__(16) u16 Bt[2][2][128 * 64];
  const int tid = threadIdx.x;
  const int w = tid >> 6, lane = tid & 63;
  const int g = lane >> 4, c16 = lane & 15;
  const int wr = w >> 2, wc = w & 3;
  const int lid = blockIdx.x;
  const int xcd = lid & 7, gg = lid >> 3;
  const int M0 = ((xcd << 3) | (gg & 7)) * 256;
  const int N0 = (gg >> 3) * 256;
  const u16* Abase = X + (size_t)M0 * 1024;
  const u16* Bbase = W + (size_t)N0 * 1024;

  f32x4 acc[8][4] = {};
  GEMM8_CORE(Abase, Bbase);

  const int which = N0 >> 10;                  // 0=Q, 1=K, 2=V
  const int colbase = N0 & 1023;
#pragma unroll
  for (int m = 0; m < 8; ++m) {
#pragma unroll
    for (int n = 0; n < 4; ++n) {
#pragma unroll
      for (int r = 0; r < 4; ++r) {
        int gm  = M0 + wr * 128 + m * 16 + 4 * g + r;
        int col = colbase + wc * 64 + n * 16 + c16;
        u16 hv = f2bf(acc[m][n][r]);
        if (which == 0) {
          Qo[(size_t)gm * 1024 + col] = hv;
        } else if (which == 1) {
          Ko[(size_t)gm * 1024 + col] = hv;
        } else {
          int b = gm >> 12, s2 = gm & 4095;
          VTo[((size_t)((b << 10) + col)) * 4096 + s2] = hv;
        }
      }
    }
  }
}

// ---------------- S-GEMM + exp: 256x256 causal tiles, 8-phase, XCD-chunked ----------------
__global__ __launch_bounds__(512, 1)
void sgemm_exp(const u16* __restrict__ Q, const u16* __restrict__ K,
               u16* __restrict__ Spack, float* __restrict__ lpart) {
  __shared__ __align__(16) u16 At[2][2][128 * 64];
  __shared__ __align__(16) u16 Bt[2][2][128 * 64];
  __shared__ float lsum[256][4];
  const int tid = threadIdx.x;
  const int w = tid >> 6, lane = tid & 63;
  const int g = lane >> 4, c16 = lane & 15;
  const int wr = w >> 2, wc = w & 3;
  const int b = blockIdx.y;

  int L = (blockIdx.x & 7) * 17 + (blockIdx.x >> 3);   // bijective XCD chunking
  int qt = 0;
  while ((qt + 1) * (qt + 2) / 2 <= L) ++qt;
  const int kt = L - qt * (qt + 1) / 2;

  const u16* Abase = Q + (size_t)b * 4096 * 1024 + (size_t)qt * 256 * 1024;
  const u16* Bbase = K + (size_t)b * 4096 * 1024 + (size_t)kt * 256 * 1024;

  f32x4 acc[8][4] = {};
  GEMM8_CORE(Abase, Bbase);

  // epilogue: exp + mask, store into 128-tile packed layout, row-sum partials.
  const int qt128 = 2 * qt + wr;
  const int kt128 = 2 * kt + (wc >> 1);
  const bool exists = (kt128 <= qt128);
  u16* Sb = Spack + (((size_t)b * 528 + (size_t)(qt128 * (qt128 + 1)) / 2 + kt128) << 14);
  const int q0 = qt * 256, k0g = kt * 256;
  float psum[8][4];
#pragma unroll
  for (int m = 0; m < 8; ++m)
#pragma unroll
    for (int r = 0; r < 4; ++r) psum[m][r] = 0.f;
#pragma unroll
  for (int m = 0; m < 8; ++m) {
#pragma unroll
    for (int n = 0; n < 4; ++n) {
#pragma unroll
      for (int r = 0; r < 4; ++r) {
        int rl = wr * 128 + m * 16 + 4 * g + r;
        int cl = wc * 64 + n * 16 + c16;
        float s = acc[m][n][r] * 0.03125f;     // 1/sqrt(1024)
        float p = (k0g + cl <= q0 + rl) ? __expf(s) : 0.f;
        u16 pb = f2bf(p);
        if (exists) Sb[(rl & 127) * 128 + (cl & 127)] = pb;
        psum[m][r] += bf2f(pb);
      }
    }
  }
#pragma unroll
  for (int m = 0; m < 8; ++m)
#pragma unroll
    for (int r = 0; r < 4; ++r) {
      float v = psum[m][r];
      v += __shfl_xor(v, 1, 64);
      v += __shfl_xor(v, 2, 64);
      v += __shfl_xor(v, 4, 64);
      v += __shfl_xor(v, 8, 64);
      psum[m][r] = v;
    }
  if (c16 == 0) {
#pragma unroll
    for (int m = 0; m < 8; ++m)
#pragma unroll
      for (int r = 0; r < 4; ++r)
        lsum[wr * 128 + m * 16 + 4 * g + r][wc] = psum[m][r];
  }
  __syncthreads();
  if (tid < 256) {
    float v = lsum[tid][0] + lsum[tid][1] + lsum[tid][2] + lsum[tid][3];
    lpart[((size_t)b * 4096 + q0 + tid) * 16 + kt] = v;
  }
}

// ---------------- PV GEMM: 256x128 paired q-tiles, 8-phase, fused l-reduce ----------------
__global__ __launch_bounds__(512, 1)
void pv_gemm(const u16* __restrict__ Spack, const u16* __restrict__ VT,
             const u16* __restrict__ ztile, const float* __restrict__ lpart,
             float* __restrict__ Out) {
  __shared__ __align__(16) u16 At[2][256 * 64];
  __shared__ __align__(16) u16 Bt[2][128 * 64];
  __shared__ float linv_lds[512];
  const int tid = threadIdx.x;
  const int w = tid >> 6, lane = tid & 63;
  const int g = lane >> 4, c16 = lane & 15;
  const int wm = w >> 1, wn = w & 1;           // wave tile: rows wm*64, cols wn*64
  const int pp = blockIdx.x;
  const int d0 = blockIdx.y;
  const int b  = blockIdx.z;

  const u16* Sp_b = Spack + (size_t)b * 528 * 16384;
  const u16* VTb  = VT + (size_t)b * 1024 * 4096;
  float* Ob = Out + (size_t)b * 4096 * 1024;

  // fused l-reduce
  {
    const int QTr = (tid < 256) ? pp : (15 - pp);
    const int row = QTr * 256 + (tid & 255);
    const int nt  = QTr + 1;
    const float* p = lpart + ((size_t)b * 4096 + row) * 16;
    float s = 0.f;
    for (int i = 0; i < nt; ++i) s += p[i];
    linv_lds[tid] = 1.f / s;
  }

  for (int pass = 0; pass < 2; ++pass) {
    const int QT = pass == 0 ? pp : 15 - pp;
    const int M0 = QT * 256;
    const int nsteps = (QT + 1) * 4;           // K-steps of 64 (even)
    const int niter  = nsteps >> 1;
    const int tLo = 2 * QT;
    const size_t triLo = (size_t)(tLo * (tLo + 1)) / 2;
    const size_t triHi = (size_t)((tLo + 1) * (tLo + 2)) / 2;

    f32x4 acc[4][4] = {};

    auto stA = [&](int bufi, int half, int tt) {   // half 0: rows 0-127, 1: 128-255
      const int kt128 = tt >> 1;
      const int koff = (tt & 1) * 64;
      const u16* base;
      if (half == 0) base = (kt128 <= tLo) ? Sp_b + ((triLo + kt128) << 14) : ztile;
      else           base = Sp_b + ((triHi + kt128) << 14);
#pragma unroll
      for (int i = 0; i < 2; ++i) {
        int ci = (half * 2 + i) * 512 + tid;
        int r = ci >> 3;
        int c = (ci & 7) ^ (r & 7);
        gld_lds16(base + (size_t)(r & 127) * 128 + koff + c * 8, &At[bufi][ci * 8]);
      }
    };
    auto stB = [&](int bufi, int tt) {
      const int kv0 = tt * 64;
#pragma unroll
      for (int i = 0; i < 2; ++i) {
        int ci = i * 512 + tid;
        int r = ci >> 3;
        int c = (ci & 7) ^ (r & 7);
        gld_lds16(VTb + (size_t)(d0 * 128 + r) * 4096 + kv0 + c * 8, &Bt[bufi][ci * 8]);
      }
    };

    bf16x8 af[4][2], bfr[4][2];
    auto readA = [&](int bufi, int mb) {
#pragma unroll
      for (int m = 0; m < 2; ++m)
#pragma unroll
        for (int dk = 0; dk < 2; ++dk) {
          int row = wm * 64 + (mb + m) * 16 + c16;
          int ch = dk * 4 + g;
          af[mb + m][dk] = *(const bf16x8*)&At[bufi][row * 64 + ((ch ^ (row & 7)) * 8)];
        }
    };
    auto readB = [&](int bufi, int nb) {
#pragma unroll
      for (int n = 0; n < 2; ++n)
#pragma unroll
        for (int dk = 0; dk < 2; ++dk) {
          int row = wn * 64 + (nb + n) * 16 + c16;
          int ch = dk * 4 + g;
          bfr[nb + n][dk] = *(const bf16x8*)&Bt[bufi][row * 64 + ((ch ^ (row & 7)) * 8)];
        }
    };
    auto domfma = [&](int mb, int nb) {
      __builtin_amdgcn_s_setprio(1);
#pragma unroll
      for (int dk = 0; dk < 2; ++dk)
#pragma unroll
        for (int m = 0; m < 2; ++m)
#pragma unroll
          for (int n = 0; n < 2; ++n)
            acc[mb + m][nb + n] = mfma16(af[mb + m][dk], bfr[nb + n][dk], acc[mb + m][nb + n]);
      __builtin_amdgcn_s_setprio(0);
    };

    // prologue: K-step 0 -> buf0, 1 -> buf1 (6 loads each)
    stA(0, 0, 0); stA(0, 1, 0); stB(0, 0);
    stA(1, 0, 1); stA(1, 1, 1); stB(1, 1);
    VMC(6);
    BAR();
    for (int it = 0; it < niter; ++it) {
      const bool pf = (it + 1 < niter);
      const int t2 = 2 * it + 2, t3 = 2 * it + 3;
      // P1
      readA(0, 0); readB(0, 0);
      BAR(); LGKM0();
      domfma(0, 0);
      BAR();
      // P2
      readA(0, 2);
      BAR(); LGKM0();
      domfma(2, 0);
      BAR();
      // P3 (+ stage A(t2))
      readB(0, 2);
      if (pf) { stA(0, 0, t2); stA(0, 1, t2); }
      BAR(); LGKM0();
      domfma(2, 2);
      BAR();
      // P4 (+ stage B(t2), counted wait)
      if (pf) stB(0, t2);
      BAR();
      domfma(0, 2);
      if (pf) { VMC(6); } else { VMC(0); }
      BAR();
      // P5-P8 mirror on buf1
      readA(1, 0); readB(1, 0);
      BAR(); LGKM0();
      domfma(0, 0);
      BAR();
      readA(1, 2);
      BAR(); LGKM0();
      domfma(2, 0);
      BAR();
      readB(1, 2);
      if (pf) { stA(1, 0, t3); stA(1, 1, t3); }
      BAR(); LGKM0();
      domfma(2, 2);
      BAR();
      if (pf) stB(1, t3);
      BAR();
      domfma(0, 2);
      if (pf) { VMC(6); } else { VMC(0); }
      BAR();
    }

    const float* lb = linv_lds + pass * 256;
#pragma unroll
    for (int m = 0; m < 4; ++m) {
#pragma unroll
      for (int r = 0; r < 4; ++r) {
        int rl = wm * 64 + m * 16 + 4 * g + r;
        float li = lb[rl];
#pragma unroll
        for (int n = 0; n < 4; ++n) {
          int dcol = d0 * 128 + wn * 64 + n * 16 + c16;
          Ob[(size_t)(M0 + rl) * 1024 + dcol] = acc[m][n][r] * li;
        }
      }
    }
  }
}

// ---------------- fallback attn (R1, proven 558us) ----------------
__global__ __launch_bounds__(512, 2)
void attn_kernel(const u16* __restrict__ Q, const u16* __restrict__ K,
                 const u16* __restrict__ VT, float* __restrict__ Out) {
  __shared__ u16 kv_lds[32 * 1024];
  __shared__ float s_part[4][32][33];
  __shared__ u16 p_lds[32 * 40];
  __shared__ float l_lds[32];

  const int tid = threadIdx.x;
  const int w = tid >> 6, lane = tid & 63;
  const int g = lane >> 4, c16 = lane & 15;
  const int b  = blockIdx.x & 3;
  const int qb = 127 - (blockIdx.x >> 2);
  const int qs = qb * 32;
  const int kh = w & 1, dq = w >> 1;

  const u16* Qb  = Q  + (size_t)b * 4096 * 1024;
  const u16* Kb  = K  + (size_t)b * 4096 * 1024;
  const u16* VTb = VT + (size_t)b * 1024 * 4096;

  bf16x8 qfrag[2][8];
#pragma unroll
  for (int qh = 0; qh < 2; ++qh)
#pragma unroll
    for (int dk = 0; dk < 8; ++dk)
      qfrag[qh][dk] = *(const bf16x8*)(Qb + (size_t)(qs + qh * 16 + c16) * 1024
                                       + dq * 256 + dk * 32 + g * 8);

  f32x4 oacc[2][8] = {};
  if (tid < 32) l_lds[tid] = 0.f;

  const int qrow_p = tid >> 4;
  const int kk     = tid & 15;
  const int gq     = qs + qrow_p;

  for (int j = 0; j <= qb; ++j) {
    const int kv0 = j * 32;
    __syncthreads();
    uint4 rk[8];
#pragma unroll
    for (int i = 0; i < 8; ++i) {
      int ci = i * 512 + tid;
      int r  = ci >> 7;
      int c  = (ci & 127) ^ (r & 7);
      rk[i] = *(const uint4*)(Kb + (size_t)(kv0 + r) * 1024 + c * 8);
    }
#pragma unroll
    for (int i = 0; i < 8; ++i)
      *(uint4*)&kv_lds[(size_t)(i * 512 + tid) * 8] = rk[i];
    __syncthreads();
    f32x4 sacc[2] = {};
#pragma unroll
    for (int dk = 0; dk < 8; ++dk) {
      int kvrow = kh * 16 + c16;
      int ch    = dq * 32 + dk * 4 + g;
      bf16x8 kf = *(const bf16x8*)&kv_lds[kvrow * 1024 + ((ch ^ (kvrow & 7)) * 8)];
      sacc[0] = mfma16(qfrag[0][dk], kf, sacc[0]);
      sacc[1] = mfma16(qfrag[1][dk], kf, sacc[1]);
    }
#pragma unroll
    for (int qh = 0; qh < 2; ++qh)
#pragma unroll
      for (int r = 0; r < 4; ++r)
        s_part[dq][qh * 16 + 4 * g + r][kh * 16 + c16] = sacc[qh][r];
    __syncthreads();
    uint4 rv[8];
#pragma unroll
    for (int i = 0; i < 8; ++i) {
      int ci = i * 512 + tid;
      int d  = ((ci >> 6) << 4) + (ci & 15);
      int c  = (ci >> 4) & 3;
      rv[i] = *(const uint4*)(VTb + (size_t)d * 4096 + kv0 + c * 8);
    }
    {
      float psum = 0.f;
#pragma unroll
      for (int h = 0; h < 2; ++h) {
        int kcol = kk + h * 16;
        float s = s_part[0][qrow_p][kcol] + s_part[1][qrow_p][kcol]
                + s_part[2][qrow_p][kcol] + s_part[3][qrow_p][kcol];
        s *= 0.03125f;
        float p = (kv0 + kcol <= gq) ? __expf(s) : 0.f;
        u16 pb = f2bf(p);
        p_lds[qrow_p * 40 + kcol] = pb;
        psum += bf2f(pb);
      }
#pragma unroll
      for (int off = 1; off < 16; off <<= 1)
        psum += __shfl_xor(psum, off, 64);
      if (kk == 0) l_lds[qrow_p] += psum;
    }
#pragma unroll
    for (int i = 0; i < 8; ++i)
      *(uint4*)&kv_lds[(size_t)(i * 512 + tid) * 8] = rv[i];
    __syncthreads();
    bf16x8 pa0 = *(const bf16x8*)&p_lds[(0  + c16) * 40 + g * 8];
    bf16x8 pa1 = *(const bf16x8*)&p_lds[(16 + c16) * 40 + g * 8];
#pragma unroll
    for (int f = 0; f < 8; ++f) {
      int dcol = w * 128 + f * 16 + c16;
      int pos  = (dcol >> 4) * 64 + g * 16 + (dcol & 15);
      bf16x8 vf = *(const bf16x8*)&kv_lds[(size_t)pos * 8];
      oacc[0][f] = mfma16(pa0, vf, oacc[0][f]);
      oacc[1][f] = mfma16(pa1, vf, oacc[1][f]);
    }
  }

  float* Ob = Out + (size_t)b * 4096 * 1024;
#pragma unroll
  for (int qh = 0; qh < 2; ++qh) {
#pragma unroll
    for (int r = 0; r < 4; ++r) {
      int ql = qh * 16 + 4 * g + r;
      float linvv = 1.f / l_lds[ql];
#pragma unroll
      for (int f = 0; f < 8; ++f)
        Ob[(size_t)(qs + ql) * 1024 + w * 128 + f * 16 + c16] = oacc[qh][f][r] * linvv;
    }
  }
}

extern "C" void kernel_launch(void* const* d_in, const int* in_sizes, int n_in,
                              void* d_out, int out_size, void* d_ws, size_t ws_size,
                              hipStream_t stream) {
  const float* x  = (const float*)d_in[0];
  const float* Wq = (const float*)d_in[1];
  const float* Wk = (const float*)d_in[2];
  const float* Wv = (const float*)d_in[3];
  float* out = (float*)d_out;

  u16* ws    = (u16*)d_ws;
  u16* wWqkv = ws;                                   // 3M elems
  u16* wX    = wWqkv + (size_t)3 * 1024 * 1024;
  u16* wQ    = wX + (size_t)16384 * 1024;
  u16* wK    = wQ + (size_t)16384 * 1024;
  u16* wVT   = wK + (size_t)16384 * 1024;            // [4][1024][4096]
  u16* wSp   = wVT + (size_t)16384 * 1024;           // packed 128-tile triangle
  float* lpart = (float*)(ws + (size_t)104857600);   // 16384*16 f32 (1MB)
  u16* wZt   = ws + (size_t)105906176;               // 32KB zero tile (dead old-linv slot)

  cast_all<<<dim3(9736), 256, 0, stream>>>(x, Wq, Wk, Wv, wX, wWqkv, wZt);

  qkv_gemm<<<dim3(768), 512, 0, stream>>>(wX, wWqkv, wQ, wK, wVT);

  if (ws_size >= (size_t)211877888) {
    sgemm_exp<<<dim3(136, 4), 512, 0, stream>>>(wQ, wK, wSp, lpart);
    pv_gemm<<<dim3(8, 8, 4), 512, 0, stream>>>(wSp, wVT, wZt, lpart, out);
  } else {
    attn_kernel<<<dim3(512), 512, 0, stream>>>(wQ, wK, wVT, out);
  }
}